// Round 2
// baseline (21181.917 us; speedup 1.0000x reference)
//
#include <hip/hip_runtime.h>

// ---------------------------------------------------------------------------
// NS_Flashed_TotalSimRetina — GLM retina simulation.
// Round 2: same structure as round 1, but inputs/outputs are FLOAT32 (the
// reference builds every float tensor as jnp.float32; round 1 read them as
// bf16 pairs, which injects Inf/NaN bit patterns -> the observed NaN).
// One workgroup per batch (batches independent), f16 spike-window ring in
// LDS, v_dot2_f32_f16 inner product with phase fix for odd steps.
// ---------------------------------------------------------------------------

#define NC     600   // cells
#define NPIX   4096  // 64*64
#define NBF    100   // filter taps
#define MC     20    // coupled cells per cell
#define NB     500
#define NBI    100   // initial spike bins
#define NBATCH 32
#define NSTEP  400   // NB - NBI
#define RSLOT  64    // ring slots (each slot = 2 taps packed f16x2), 128 taps
#define RPAD   65    // padded row stride in dwords

typedef unsigned int u32;
typedef _Float16 f16x2 __attribute__((ext_vector_type(2)));

__device__ __forceinline__ float dot2(u32 a, u32 b, float acc) {
  return __builtin_amdgcn_fdot2(__builtin_bit_cast(f16x2, a),
                                __builtin_bit_cast(f16x2, b), acc, false);
}

// --- stim_applied[b][c] = sum_p stim[b][p] * spat[c][p] ---------------------
__global__ void applied_kernel(const float* __restrict__ stim,
                               const float* __restrict__ spat,
                               float* __restrict__ applied) {
  const int c = blockIdx.x, b = blockIdx.y;
  __shared__ float red[256];
  float a = 0.f;
  for (int p = threadIdx.x; p < NPIX; p += 256)
    a += stim[b * NPIX + p] * spat[c * NPIX + p];
  red[threadIdx.x] = a;
  __syncthreads();
  for (int s = 128; s > 0; s >>= 1) {
    if (threadIdx.x < s) red[threadIdx.x] += red[threadIdx.x + s];
    __syncthreads();
  }
  if (threadIdx.x == 0) applied[b * NC + c] = red[0];
}

// --- convT[t][c] = sum_f stc[t+f] * tcf[c][f] (transposed for coalesced
// per-step reads in the sim kernel) -----------------------------------------
__global__ void conv_kernel(const float* __restrict__ stc,
                            const float* __restrict__ tcf,
                            float* __restrict__ convT) {
  int idx = blockIdx.x * 256 + threadIdx.x;
  if (idx >= NSTEP * NC) return;
  int t = idx / NC, c = idx - t * NC;
  float a = 0.f;
  for (int f = 0; f < NBF; ++f)
    a += stc[t + f] * tcf[c * NBF + f];
  convT[idx] = a;
}

// --- packed f16 filter table ftP[m][j][c] = (w[2j], w[2j+1]) ---------------
// m = 0..19: coupling filters, m = 20: feedback filter. Layout [m][j][c] so
// lane c reads are coalesced.
__global__ void filt_kernel(const float* __restrict__ cf,
                            const float* __restrict__ ff,
                            u32* __restrict__ ftP) {
  int idx = blockIdx.x * 256 + threadIdx.x;
  if (idx >= 21 * 50 * NC) return;
  int c = idx % NC;
  int r = idx / NC;
  int j = r % 50;
  int m = r / 50;
  float w0, w1;
  if (m < MC) {
    w0 = cf[(c * MC + m) * NBF + 2 * j];
    w1 = cf[(c * MC + m) * NBF + 2 * j + 1];
  } else {
    w0 = ff[c * NBF + 2 * j];
    w1 = ff[c * NBF + 2 * j + 1];
  }
  f16x2 v; v[0] = (_Float16)w0; v[1] = (_Float16)w1;
  ftP[idx] = __builtin_bit_cast(u32, v);
}

// --- copy initial spikes into output (first 100 bins of each row), float4 --
__global__ void copy_init_kernel(const float4* __restrict__ init,
                                 float4* __restrict__ out) {
  int idx = blockIdx.x * 256 + threadIdx.x;
  if (idx >= NBATCH * NC * (NBI / 4)) return;
  int k4 = idx % (NBI / 4);
  int bc = idx / (NBI / 4);
  out[bc * (NB / 4) + k4] = init[idx];  // out row = 500 f32 = 125 float4
}

// --- sequential simulation: one workgroup per batch ------------------------
// LDS ring: ring[c][slot] packs spikes at absolute times (2s, 2s+1) mod 128.
// Step t reads taps tau = t..t+99, writes tau = t+100 (half-slot write; the
// only concurrently-read slot sharing it is the odd-t tail, whose weight for
// that half is 0). One __syncthreads per step.
__global__ __launch_bounds__(640, 1) void sim_kernel(
    const float* __restrict__ init, const int* __restrict__ sel,
    const float* __restrict__ bias, const float* __restrict__ applied,
    const float* __restrict__ convT, const u32* __restrict__ ftP,
    float* __restrict__ out) {
  extern __shared__ u32 ring[];  // [NC][RPAD], slots 0..63 used
  const int b = blockIdx.x;
  const int tid = threadIdx.x;

  // init ring: slots 0..49 from initial spikes, 50..63 zero
  for (int idx = tid; idx < NC * (NBI / 2); idx += 640) {
    int c0 = idx / (NBI / 2), k = idx - c0 * (NBI / 2);
    f16x2 v;
    v[0] = (_Float16)init[(b * NC + c0) * NBI + 2 * k];
    v[1] = (_Float16)init[(b * NC + c0) * NBI + 2 * k + 1];
    ring[c0 * RPAD + k] = __builtin_bit_cast(u32, v);
  }
  for (int idx = tid; idx < NC * (RSLOT - NBI / 2); idx += 640) {
    int c0 = idx / (RSLOT - NBI / 2), k = idx - c0 * (RSLOT - NBI / 2);
    ring[c0 * RPAD + (NBI / 2) + k] = 0u;
  }

  int selreg[MC + 1];
  float biasv = 0.f, appv = 0.f;
  const int c = tid;
  const bool active = (c < NC);
  if (active) {
    for (int m = 0; m < MC; ++m) selreg[m] = sel[c * MC + m];
    selreg[MC] = c;  // feedback source = self, filter slot m = 20
    biasv = bias[c];
    appv  = applied[b * NC + c];
  }
  __syncthreads();

  for (int t = 0; t < NSTEP; ++t) {
    if (active) {
      float acc = biasv + appv * convT[t * NC + c];
      const int par = t & 1;
      const int slot0 = (t >> 1) & 63;
      #pragma unroll 1
      for (int m = 0; m <= MC; ++m) {
        const int src = selreg[m];
        const u32* rrow = ring + src * RPAD;
        const u32* frow = ftP + (m * 50) * NC + c;
        u32 prev = 0;
        int s = slot0;
        #pragma unroll 5
        for (int j = 0; j < 50; ++j) {
          u32 e = frow[j * NC];
          // even t: pairs aligned, use e. odd t: re-phase to (w[2j-1], w[2j]).
          u32 w = par ? ((prev >> 16) | (e << 16)) : e;
          acc = dot2(rrow[s], w, acc);
          prev = e;
          s = (s + 1) & 63;
        }
        if (par) acc = dot2(rrow[s], prev >> 16, acc);  // tail tap f=99
      }
      float spike = 1.f / (1.f + __expf(-acc));
      out[(size_t)(b * NC + c) * NB + NBI + t] = spike;
      out[(size_t)NBATCH * NC * NB + (size_t)(b * NC + c) * NSTEP + t] = acc;
      // publish spike at tau = t+100 (2-byte half-slot write)
      int tau = t + NBI;
      _Float16* rh = (_Float16*)(ring + c * RPAD + ((tau >> 1) & 63));
      rh[tau & 1] = (_Float16)spike;
    }
    __syncthreads();
  }
}

extern "C" void kernel_launch(void* const* d_in, const int* in_sizes, int n_in,
                              void* d_out, int out_size, void* d_ws, size_t ws_size,
                              hipStream_t stream) {
  const float* stim = (const float*)d_in[0];   // 32x64x64 f32
  const float* init = (const float*)d_in[1];   // 32x600x100 f32
  const float* spat = (const float*)d_in[2];   // 600x4096 f32
  const float* tcf  = (const float*)d_in[3];   // 600x100 f32
  const float* ff   = (const float*)d_in[4];   // 600x100 f32
  const float* cf   = (const float*)d_in[5];   // 600x20x100 f32
  const float* bias = (const float*)d_in[6];   // 600x1 f32
  const int*   sel  = (const int*)d_in[7];     // 600x20 int32
  const float* stc  = (const float*)d_in[8];   // 500 f32
  float* out = (float*)d_out;                  // spikes 32x600x500, gensig 32x600x400

  char* ws = (char*)d_ws;
  float* applied = (float*)ws;                              // 76,800 B
  float* convT   = (float*)(ws + 76800);                    // 960,000 B
  u32*   ftP     = (u32*)(ws + 76800 + 960000);             // 2,520,000 B
  (void)ws_size; (void)in_sizes; (void)n_in; (void)out_size;

  hipLaunchKernelGGL(applied_kernel, dim3(NC, NBATCH), dim3(256), 0, stream,
                     stim, spat, applied);
  hipLaunchKernelGGL(conv_kernel, dim3((NSTEP * NC + 255) / 256), dim3(256), 0,
                     stream, stc, tcf, convT);
  hipLaunchKernelGGL(filt_kernel, dim3((21 * 50 * NC + 255) / 256), dim3(256), 0,
                     stream, cf, ff, ftP);
  hipLaunchKernelGGL(copy_init_kernel,
                     dim3((NBATCH * NC * (NBI / 4) + 255) / 256), dim3(256), 0,
                     stream, (const float4*)init, (float4*)out);

  // 156 KB dynamic LDS (> default 64 KB cap) — opt in every call (capture-safe)
  hipFuncSetAttribute(reinterpret_cast<const void*>(sim_kernel),
                      hipFuncAttributeMaxDynamicSharedMemorySize,
                      NC * RPAD * 4);
  hipLaunchKernelGGL(sim_kernel, dim3(NBATCH), dim3(640), NC * RPAD * 4, stream,
                     init, sel, bias, applied, convT, ftP, out);
}